// Round 1
// baseline (1785.328 us; speedup 1.0000x reference)
//
#include <hip/hip_runtime.h>

#define N_NODES_C 50000
#define N_EDGES_C 1600000
#define EPS_C 1e-5f

// ---------------------------------------------------------------------------
// Edge MLP: in[96] = [edge_attr(16), x[src](32), x[dst](32), u(16)]
//   h = relu(in @ W1 + b1)  (128)
//   o = relu(h @ W2 + b2)   (16)
//   o = LayerNorm(o) * g + bt
// Also scatter-adds o into agg[dst] and 1 into cnt[dst].
// Hidden processed in 2 chunks of 64 registers; inputs re-read per chunk
// (L1/L2-resident). All per-thread arrays statically indexed (no scratch).
// ---------------------------------------------------------------------------
__global__ __launch_bounds__(256) void edge_kernel(
    const float* __restrict__ x, const float* __restrict__ ea,
    const float* __restrict__ u, const int* __restrict__ src,
    const int* __restrict__ dst,
    const float* __restrict__ W1, const float* __restrict__ b1,
    const float* __restrict__ W2, const float* __restrict__ b2,
    const float* __restrict__ gamma, const float* __restrict__ beta,
    float* __restrict__ e_out, float* __restrict__ agg, float* __restrict__ cnt)
{
    const int e = blockIdx.x * 256 + threadIdx.x;
    if (e >= N_EDGES_C) return;
    const int s = src[e];
    const int d = dst[e];

    float acc2[16];
#pragma unroll
    for (int j = 0; j < 16; j++) acc2[j] = b2[j];

#pragma unroll 1
    for (int c = 0; c < 2; c++) {
        float h[64];
#pragma unroll
        for (int j = 0; j < 64; j++) h[j] = b1[c * 64 + j];

#pragma unroll 1
        for (int r = 0; r < 6; r++) {
            const float* base;
            switch (r) {
                case 0:  base = ea + (size_t)e * 16;      break;
                case 1:  base = x + (size_t)s * 32;       break;
                case 2:  base = x + (size_t)s * 32 + 16;  break;
                case 3:  base = x + (size_t)d * 32;       break;
                case 4:  base = x + (size_t)d * 32 + 16;  break;
                default: base = u;                        break;
            }
            float seg[16];
#pragma unroll
            for (int q = 0; q < 4; q++) {
                float4 t = reinterpret_cast<const float4*>(base)[q];
                seg[4 * q + 0] = t.x; seg[4 * q + 1] = t.y;
                seg[4 * q + 2] = t.z; seg[4 * q + 3] = t.w;
            }
            const float* Wb = W1 + (size_t)(r * 16) * 128 + c * 64;
#pragma unroll
            for (int kk = 0; kk < 16; kk++) {
#pragma unroll
                for (int j = 0; j < 64; j++)
                    h[j] = fmaf(seg[kk], Wb[(size_t)kk * 128 + j], h[j]);
            }
        }
        const float* W2b = W2 + (size_t)c * 64 * 16;
#pragma unroll
        for (int j = 0; j < 64; j++) {
            float hv = fmaxf(h[j], 0.f);
#pragma unroll
            for (int j2 = 0; j2 < 16; j2++)
                acc2[j2] = fmaf(hv, W2b[(size_t)j * 16 + j2], acc2[j2]);
        }
    }

#pragma unroll
    for (int j = 0; j < 16; j++) acc2[j] = fmaxf(acc2[j], 0.f);

    // LayerNorm over 16
    float mu = 0.f;
#pragma unroll
    for (int j = 0; j < 16; j++) mu += acc2[j];
    mu *= (1.f / 16.f);
    float var = 0.f;
#pragma unroll
    for (int j = 0; j < 16; j++) { float t = acc2[j] - mu; var += t * t; }
    var *= (1.f / 16.f);
    const float rs = rsqrtf(var + EPS_C);
#pragma unroll
    for (int j = 0; j < 16; j++)
        acc2[j] = (acc2[j] - mu) * rs * gamma[j] + beta[j];

    // store e_out (4x float4)
    float4* eo = reinterpret_cast<float4*>(e_out + (size_t)e * 16);
#pragma unroll
    for (int q = 0; q < 4; q++) {
        float4 t;
        t.x = acc2[4 * q + 0]; t.y = acc2[4 * q + 1];
        t.z = acc2[4 * q + 2]; t.w = acc2[4 * q + 3];
        eo[q] = t;
    }

    // scatter-add into receiver node
    float* ag = agg + (size_t)d * 16;
#pragma unroll
    for (int j = 0; j < 16; j++) atomicAdd(&ag[j], acc2[j]);
    atomicAdd(&cnt[d], 1.f);
}

// ---------------------------------------------------------------------------
// Node MLP: in[64] = [x(32), agg/max(cnt,1)(16), u(16)]
//   h = relu(in @ W1 + b1) (128); o = relu(h @ W2 + b2) (32); LayerNorm
// ---------------------------------------------------------------------------
__global__ __launch_bounds__(256) void node_kernel(
    const float* __restrict__ x, const float* __restrict__ u,
    const float* __restrict__ W1, const float* __restrict__ b1,
    const float* __restrict__ W2, const float* __restrict__ b2,
    const float* __restrict__ gamma, const float* __restrict__ beta,
    const float* __restrict__ agg, const float* __restrict__ cnt,
    float* __restrict__ x_out)
{
    const int n = blockIdx.x * 256 + threadIdx.x;
    if (n >= N_NODES_C) return;
    const float rcp = 1.f / fmaxf(cnt[n], 1.f);

    float acc2[32];
#pragma unroll
    for (int j = 0; j < 32; j++) acc2[j] = b2[j];

#pragma unroll 1
    for (int c = 0; c < 2; c++) {
        float h[64];
#pragma unroll
        for (int j = 0; j < 64; j++) h[j] = b1[c * 64 + j];

#pragma unroll 1
        for (int r = 0; r < 4; r++) {
            const float* base;
            switch (r) {
                case 0:  base = x + (size_t)n * 32;       break;
                case 1:  base = x + (size_t)n * 32 + 16;  break;
                case 2:  base = agg + (size_t)n * 16;     break;
                default: base = u;                        break;
            }
            float seg[16];
#pragma unroll
            for (int q = 0; q < 4; q++) {
                float4 t = reinterpret_cast<const float4*>(base)[q];
                seg[4 * q + 0] = t.x; seg[4 * q + 1] = t.y;
                seg[4 * q + 2] = t.z; seg[4 * q + 3] = t.w;
            }
            if (r == 2) {
#pragma unroll
                for (int q = 0; q < 16; q++) seg[q] *= rcp;
            }
            const float* Wb = W1 + (size_t)(r * 16) * 128 + c * 64;
#pragma unroll
            for (int kk = 0; kk < 16; kk++) {
#pragma unroll
                for (int j = 0; j < 64; j++)
                    h[j] = fmaf(seg[kk], Wb[(size_t)kk * 128 + j], h[j]);
            }
        }
        const float* W2b = W2 + (size_t)c * 64 * 32;
#pragma unroll
        for (int j = 0; j < 64; j++) {
            float hv = fmaxf(h[j], 0.f);
#pragma unroll
            for (int j2 = 0; j2 < 32; j2++)
                acc2[j2] = fmaf(hv, W2b[(size_t)j * 32 + j2], acc2[j2]);
        }
    }

#pragma unroll
    for (int j = 0; j < 32; j++) acc2[j] = fmaxf(acc2[j], 0.f);

    float mu = 0.f;
#pragma unroll
    for (int j = 0; j < 32; j++) mu += acc2[j];
    mu *= (1.f / 32.f);
    float var = 0.f;
#pragma unroll
    for (int j = 0; j < 32; j++) { float t = acc2[j] - mu; var += t * t; }
    var *= (1.f / 32.f);
    const float rs = rsqrtf(var + EPS_C);
#pragma unroll
    for (int j = 0; j < 32; j++)
        acc2[j] = (acc2[j] - mu) * rs * gamma[j] + beta[j];

    float4* xo = reinterpret_cast<float4*>(x_out + (size_t)n * 32);
#pragma unroll
    for (int q = 0; q < 8; q++) {
        float4 t;
        t.x = acc2[4 * q + 0]; t.y = acc2[4 * q + 1];
        t.z = acc2[4 * q + 2]; t.w = acc2[4 * q + 3];
        xo[q] = t;
    }
}

// ---------------------------------------------------------------------------
// Column-sum of a [rows x COLS] matrix into per-block partials [gridDim x COLS]
// ---------------------------------------------------------------------------
template <int COLS>
__global__ __launch_bounds__(256) void colsum_kernel(
    const float* __restrict__ src, int rows, float* __restrict__ part)
{
    float acc[COLS];
#pragma unroll
    for (int c = 0; c < COLS; c++) acc[c] = 0.f;

    const int stride = gridDim.x * 256;
    for (int r = blockIdx.x * 256 + threadIdx.x; r < rows; r += stride) {
        const float4* p = reinterpret_cast<const float4*>(src + (size_t)r * COLS);
#pragma unroll
        for (int q = 0; q < COLS / 4; q++) {
            float4 t = p[q];
            acc[4 * q + 0] += t.x; acc[4 * q + 1] += t.y;
            acc[4 * q + 2] += t.z; acc[4 * q + 3] += t.w;
        }
    }

    // intra-wave reduce (64 lanes)
#pragma unroll
    for (int c = 0; c < COLS; c++) {
#pragma unroll
        for (int off = 32; off > 0; off >>= 1)
            acc[c] += __shfl_down(acc[c], off);
    }

    __shared__ float smem[4][COLS];
    const int wave = threadIdx.x >> 6;
    const int lane = threadIdx.x & 63;
    if (lane == 0) {
#pragma unroll
        for (int c = 0; c < COLS; c++) smem[wave][c] = acc[c];
    }
    __syncthreads();
    if (threadIdx.x < COLS) {
        float s = smem[0][threadIdx.x] + smem[1][threadIdx.x] +
                  smem[2][threadIdx.x] + smem[3][threadIdx.x];
        part[(size_t)blockIdx.x * COLS + threadIdx.x] = s;
    }
}

// ---------------------------------------------------------------------------
// Global MLP: in[64] = [u(16), mean(x_out)(32), mean(e_out)(16)]
//   h = relu(in @ W1 + b1) (128); o = relu(h @ W2 + b2) (16)  [no LayerNorm]
// One block of 128 threads.
// ---------------------------------------------------------------------------
__global__ __launch_bounds__(128) void global_kernel(
    const float* __restrict__ u,
    const float* __restrict__ W1, const float* __restrict__ b1,
    const float* __restrict__ W2, const float* __restrict__ b2,
    const float* __restrict__ epart, int nEpart,
    const float* __restrict__ xpart, int nXpart,
    float* __restrict__ u_out)
{
    __shared__ float gin[64];
    __shared__ float h[128];
    const int t = threadIdx.x;

    if (t < 16) {
        gin[t] = u[t];
    } else if (t < 48) {
        const int c = t - 16;
        float s = 0.f;
        for (int p = 0; p < nXpart; p++) s += xpart[(size_t)p * 32 + c];
        gin[16 + c] = s * (1.f / (float)N_NODES_C);
    } else if (t < 64) {
        const int c = t - 48;
        float s = 0.f;
        for (int p = 0; p < nEpart; p++) s += epart[(size_t)p * 16 + c];
        gin[48 + c] = s * (1.f / (float)N_EDGES_C);
    }
    __syncthreads();

    float hv = b1[t];
    for (int k = 0; k < 64; k++) hv = fmaf(gin[k], W1[(size_t)k * 128 + t], hv);
    h[t] = fmaxf(hv, 0.f);
    __syncthreads();

    if (t < 16) {
        float o = b2[t];
        for (int j = 0; j < 128; j++) o = fmaf(h[j], W2[(size_t)j * 16 + t], o);
        u_out[t] = fmaxf(o, 0.f);
    }
}

// ---------------------------------------------------------------------------
extern "C" void kernel_launch(void* const* d_in, const int* in_sizes, int n_in,
                              void* d_out, int out_size, void* d_ws, size_t ws_size,
                              hipStream_t stream)
{
    const float* x    = (const float*)d_in[0];
    const float* ea   = (const float*)d_in[1];
    const float* u    = (const float*)d_in[2];
    const int*   src  = (const int*)d_in[3];
    const int*   dst  = (const int*)d_in[4];
    const float* eW1  = (const float*)d_in[5];
    const float* eb1  = (const float*)d_in[6];
    const float* eW2  = (const float*)d_in[7];
    const float* eb2  = (const float*)d_in[8];
    const float* eg   = (const float*)d_in[9];
    const float* ebt  = (const float*)d_in[10];
    const float* nW1  = (const float*)d_in[11];
    const float* nb1  = (const float*)d_in[12];
    const float* nW2  = (const float*)d_in[13];
    const float* nb2  = (const float*)d_in[14];
    const float* ng   = (const float*)d_in[15];
    const float* nbt  = (const float*)d_in[16];
    const float* gW1  = (const float*)d_in[17];
    const float* gb1  = (const float*)d_in[18];
    const float* gW2  = (const float*)d_in[19];
    const float* gb2  = (const float*)d_in[20];

    float* x_out = (float*)d_out;                              // 50000*32
    float* e_out = (float*)d_out + (size_t)N_NODES_C * 32;     // 1.6M*16
    float* u_out = e_out + (size_t)N_EDGES_C * 16;             // 16

    // workspace layout (floats)
    float* agg   = (float*)d_ws;                 // 50000*16 = 800000
    float* cnt   = agg + 800000;                 // 50000
    float* epart = cnt + 50000;                  // 256*16 = 4096
    float* xpart = epart + 256 * 16;             // 64*32  = 2048

    // zero the atomic accumulators (agg + cnt) every launch
    hipMemsetAsync(d_ws, 0, (size_t)(800000 + 50000) * sizeof(float), stream);

    edge_kernel<<<N_EDGES_C / 256, 256, 0, stream>>>(
        x, ea, u, src, dst, eW1, eb1, eW2, eb2, eg, ebt, e_out, agg, cnt);

    colsum_kernel<16><<<256, 256, 0, stream>>>(e_out, N_EDGES_C, epart);

    node_kernel<<<(N_NODES_C + 255) / 256, 256, 0, stream>>>(
        x, u, nW1, nb1, nW2, nb2, ng, nbt, agg, cnt, x_out);

    colsum_kernel<32><<<64, 256, 0, stream>>>(x_out, N_NODES_C, xpart);

    global_kernel<<<1, 128, 0, stream>>>(
        u, gW1, gb1, gW2, gb2, epart, 256, xpart, 64, u_out);
}

// Round 3
// 470.080 us; speedup vs baseline: 3.7979x; 3.7979x over previous
//
#include <hip/hip_runtime.h>

#define N_NODES_C 50000
#define N_EDGES_C 1600000
#define EPS_C 1e-5f

typedef __attribute__((ext_vector_type(8))) short bf16x8;
typedef __attribute__((ext_vector_type(4))) float f32x4;

static __device__ __forceinline__ unsigned short rne_bf(float f) {
    union { float f; unsigned int u; } v; v.f = f;
    unsigned int r = v.u + 0x7fffu + ((v.u >> 16) & 1u);  // RNE
    return (unsigned short)(r >> 16);
}
static __device__ __forceinline__ float bf2f(unsigned short h) {
    union { unsigned int u; float f; } v; v.u = ((unsigned int)h) << 16;
    return v.f;
}
static __device__ __forceinline__ void splitf(float x, short& hi, short& lo) {
    unsigned short h = rne_bf(x);
    hi = (short)h;
    lo = (short)rne_bf(x - bf2f(h));
}
static __device__ __forceinline__ void ld8split(const float* p, float scale,
                                                bf16x8& hi, bf16x8& lo) {
    float4 a = *reinterpret_cast<const float4*>(p);
    float4 b = *reinterpret_cast<const float4*>(p + 4);
    float v[8] = {a.x, a.y, a.z, a.w, b.x, b.y, b.z, b.w};
#pragma unroll
    for (int i = 0; i < 8; ++i) {
        short h, l;
        splitf(v[i] * scale, h, l);
        hi[i] = h; lo[i] = l;
    }
}

// 3-term split product: acc += (Ah+Al)@(Bh+Bl) minus lo@lo
#define MFMA3(acc, wh, wl, bh, bl)                                            \
    acc = __builtin_amdgcn_mfma_f32_16x16x32_bf16(wh, bh, acc, 0, 0, 0);      \
    acc = __builtin_amdgcn_mfma_f32_16x16x32_bf16(wl, bh, acc, 0, 0, 0);      \
    acc = __builtin_amdgcn_mfma_f32_16x16x32_bf16(wh, bl, acc, 0, 0, 0);

// ===========================================================================
// Edge MLP, hidden-split across 4 waves (wave w owns cols [32w,32w+32)).
// Layer-1 computed as h^T = W1^T @ in^T:
//   mfma(A,B,C): A-frag lane(g,c): A[c][8g+j]; B-frag: B[8g+j][c];
//   D lane: D[4g+r][c].  => D = h^T tile: lane holds h[edge=c][hid=...4g+r].
// Layer-2 K-split partials reduced across waves via LDS (dbuf, 1 barrier/it).
// ===========================================================================
__global__ __launch_bounds__(256, 1) void edge_kernel(
    const float* __restrict__ x, const float* __restrict__ ea,
    const float* __restrict__ u, const int* __restrict__ src,
    const int* __restrict__ dst,
    const float* __restrict__ W1, const float* __restrict__ b1,
    const float* __restrict__ W2, const float* __restrict__ b2,
    const float* __restrict__ gamma, const float* __restrict__ beta,
    float* __restrict__ e_out, float* __restrict__ agg, float* __restrict__ cnt,
    float* __restrict__ esum)
{
    // per-wave hidden slab: [wave][edge-row 32][hi/lo][k-local 32 pad 40]
    __shared__ __attribute__((aligned(16))) unsigned short hs[4][32][2][40];
    // cross-wave layer-2 partials, double-buffered: [buf][wave][edge 32][col pad 20]
    __shared__ float red[2][4][32][20];
    __shared__ float esr[4][16];

    const int tid = threadIdx.x;
    const int w = tid >> 6, l = tid & 63, g = l >> 4, c = l & 15;
    const int csw = c >> 2;  // LDS k-group swizzle key

    // ---- W1 fragments (this wave's 2 hidden n-tiles), hi/lo, in registers
    bf16x8 w1h[3][2], w1l[3][2];
#pragma unroll
    for (int kk = 0; kk < 3; ++kk)
#pragma unroll
        for (int nt = 0; nt < 2; ++nt) {
            bf16x8 h, lo;
#pragma unroll
            for (int j = 0; j < 8; ++j) {
                float f = W1[(size_t)(32 * kk + 8 * g + j) * 128 + 32 * w + 16 * nt + c];
                short sh, sl; splitf(f, sh, sl);
                h[j] = sh; lo[j] = sl;
            }
            w1h[kk][nt] = h; w1l[kk][nt] = lo;
        }

    // ---- W2 slice fragments (K rows [32w,32w+32)), hi/lo
    bf16x8 w2h, w2l;
    {
        bf16x8 h, lo;
#pragma unroll
        for (int j = 0; j < 8; ++j) {
            float f = W2[(size_t)(32 * w + 8 * g + j) * 16 + c];
            short sh, sl; splitf(f, sh, sl);
            h[j] = sh; lo[j] = sl;
        }
        w2h = h; w2l = lo;
    }

    // ---- b1 values this lane produces: hid = 32w + 16nt + 4g + r
    float b1v[2][4];
#pragma unroll
    for (int nt = 0; nt < 2; ++nt)
#pragma unroll
        for (int r = 0; r < 4; ++r)
            b1v[nt][r] = b1[32 * w + 16 * nt + 4 * g + r];

    // ---- epilogue constants (thread handles output col = tid&15)
    const int ecol = tid & 15;
    const float b2c = b2[ecol], gc = gamma[ecol], btc = beta[ecol];

    float esl = 0.f;
    const int base = blockIdx.x * 800;  // 2000 blocks * 25 iters * 32 edges

#pragma unroll 1
    for (int i = 0; i < 25; ++i) {
        const int ebase = base + i * 32;
        const int e0 = ebase + c, e1 = ebase + 16 + c;
        const int s0 = src[e0], s1 = src[e1];
        const int d0v = dst[e0], d1v = dst[e1];

        f32x4 acc[2][2];
#pragma unroll
        for (int t = 0; t < 2; ++t)
#pragma unroll
            for (int nt = 0; nt < 2; ++nt) {
                f32x4 z = {0.f, 0.f, 0.f, 0.f};
                acc[t][nt] = z;
            }

        // ---- layer 1: K=96 in 3 steps, full split (3 MFMAs per product)
        {   // kk=0: g<2 -> ea[e][8g], g>=2 -> x[src][8(g-2)]
            const float* p0 = (g < 2) ? (ea + (size_t)e0 * 16 + 8 * g)
                                      : (x + (size_t)s0 * 32 + 8 * (g - 2));
            const float* p1 = (g < 2) ? (ea + (size_t)e1 * 16 + 8 * g)
                                      : (x + (size_t)s1 * 32 + 8 * (g - 2));
            bf16x8 bh0, bl0, bh1, bl1;
            ld8split(p0, 1.f, bh0, bl0); ld8split(p1, 1.f, bh1, bl1);
#pragma unroll
            for (int nt = 0; nt < 2; ++nt) {
                MFMA3(acc[0][nt], w1h[0][nt], w1l[0][nt], bh0, bl0);
                MFMA3(acc[1][nt], w1h[0][nt], w1l[0][nt], bh1, bl1);
            }
        }
        {   // kk=1: g<2 -> x[src][16+8g], g>=2 -> x[dst][8(g-2)]
            const float* p0 = (g < 2) ? (x + (size_t)s0 * 32 + 16 + 8 * g)
                                      : (x + (size_t)d0v * 32 + 8 * (g - 2));
            const float* p1 = (g < 2) ? (x + (size_t)s1 * 32 + 16 + 8 * g)
                                      : (x + (size_t)d1v * 32 + 8 * (g - 2));
            bf16x8 bh0, bl0, bh1, bl1;
            ld8split(p0, 1.f, bh0, bl0); ld8split(p1, 1.f, bh1, bl1);
#pragma unroll
            for (int nt = 0; nt < 2; ++nt) {
                MFMA3(acc[0][nt], w1h[1][nt], w1l[1][nt], bh0, bl0);
                MFMA3(acc[1][nt], w1h[1][nt], w1l[1][nt], bh1, bl1);
            }
        }
        {   // kk=2: g<2 -> x[dst][16+8g], g>=2 -> u[8(g-2)]
            const float* p0 = (g < 2) ? (x + (size_t)d0v * 32 + 16 + 8 * g)
                                      : (u + 8 * (g - 2));
            const float* p1 = (g < 2) ? (x + (size_t)d1v * 32 + 16 + 8 * g)
                                      : (u + 8 * (g - 2));
            bf16x8 bh0, bl0, bh1, bl1;
            ld8split(p0, 1.f, bh0, bl0); ld8split(p1, 1.f, bh1, bl1);
#pragma unroll
            for (int nt = 0; nt < 2; ++nt) {
                MFMA3(acc[0][nt], w1h[2][nt], w1l[2][nt], bh0, bl0);
                MFMA3(acc[1][nt], w1h[2][nt], w1l[2][nt], bh1, bl1);
            }
        }

        // ---- bias + ReLU + hi/lo split -> per-wave slab (k-major per edge)
        // lane holds h[edge=16t+c][klocal=16nt+4g+r]; write 4 shorts per (t,nt,hl)
        // k-group-of-8 swizzled by c>>2 to spread banks.
#pragma unroll
        for (int t = 0; t < 2; ++t)
#pragma unroll
            for (int nt = 0; nt < 2; ++nt) {
                short4 hi4, lo4;
                float v0 = fmaxf(acc[t][nt][0] + b1v[nt][0], 0.f);
                float v1 = fmaxf(acc[t][nt][1] + b1v[nt][1], 0.f);
                float v2 = fmaxf(acc[t][nt][2] + b1v[nt][2], 0.f);
                float v3 = fmaxf(acc[t][nt][3] + b1v[nt][3], 0.f);
                splitf(v0, hi4.x, lo4.x); splitf(v1, hi4.y, lo4.y);
                splitf(v2, hi4.z, lo4.z); splitf(v3, hi4.w, lo4.w);
                const int grp = ((2 * nt + (g >> 1)) ^ csw) * 8 + 4 * (g & 1);
                *reinterpret_cast<short4*>(&hs[w][16 * t + c][0][grp]) = hi4;
                *reinterpret_cast<short4*>(&hs[w][16 * t + c][1][grp]) = lo4;
            }

        // ---- layer 2 (this wave's K=32 slice), split product
        f32x4 acc2[2];
#pragma unroll
        for (int t = 0; t < 2; ++t) { f32x4 z = {0.f, 0.f, 0.f, 0.f}; acc2[t] = z; }
#pragma unroll
        for (int t = 0; t < 2; ++t) {
            const int rg = (g ^ csw) * 8;
            bf16x8 a2h = *reinterpret_cast<const bf16x8*>(&hs[w][16 * t + c][0][rg]);
            bf16x8 a2l = *reinterpret_cast<const bf16x8*>(&hs[w][16 * t + c][1][rg]);
            acc2[t] = __builtin_amdgcn_mfma_f32_16x16x32_bf16(a2h, w2h, acc2[t], 0, 0, 0);
            acc2[t] = __builtin_amdgcn_mfma_f32_16x16x32_bf16(a2l, w2h, acc2[t], 0, 0, 0);
            acc2[t] = __builtin_amdgcn_mfma_f32_16x16x32_bf16(a2h, w2l, acc2[t], 0, 0, 0);
        }

        // ---- cross-wave partial reduce (dbuf; one barrier per iter)
        const int ib = i & 1;
#pragma unroll
        for (int t = 0; t < 2; ++t)
#pragma unroll
            for (int r = 0; r < 4; ++r)
                red[ib][w][16 * t + 4 * g + r][c] = acc2[t][r];
        __syncthreads();

        // ---- epilogue: 256 threads x 2 rows; bias, ReLU, LN(16), stores
#pragma unroll
        for (int pass = 0; pass < 2; ++pass) {
            const int erow = (tid >> 4) + 16 * pass;  // 0..31
            float o = red[ib][0][erow][ecol] + red[ib][1][erow][ecol] +
                      red[ib][2][erow][ecol] + red[ib][3][erow][ecol] + b2c;
            o = fmaxf(o, 0.f);
            float s = o, q = o * o;
            s += __shfl_xor(s, 1);  q += __shfl_xor(q, 1);
            s += __shfl_xor(s, 2);  q += __shfl_xor(q, 2);
            s += __shfl_xor(s, 4);  q += __shfl_xor(q, 4);
            s += __shfl_xor(s, 8);  q += __shfl_xor(q, 8);
            const float mu = s * 0.0625f;
            const float var = fmaxf(q * 0.0625f - mu * mu, 0.f);
            const float val = (o - mu) * rsqrtf(var + EPS_C) * gc + btc;
            const int e2 = ebase + erow;
            e_out[(size_t)e2 * 16 + ecol] = val;
            const int d2 = dst[e2];
            atomicAdd(&agg[(size_t)d2 * 16 + ecol], val);
            if (ecol == 0) atomicAdd(&cnt[d2], 1.f);
            esl += val;
        }
    }

    // ---- fused e_out column-sum (lanes share ecol pattern l&15)
    esl += __shfl_xor(esl, 16);
    esl += __shfl_xor(esl, 32);
    if (l < 16) esr[w][c] = esl;
    __syncthreads();
    if (tid < 16) atomicAdd(&esum[tid], esr[0][tid] + esr[1][tid] + esr[2][tid] + esr[3][tid]);
}

// ===========================================================================
// Node MLP, same template. in[64] = [x(32), agg*rcp(16), u(16)], out 32 + LN.
// One 32-node tile per block.
// ===========================================================================
__global__ __launch_bounds__(256, 1) void node_kernel(
    const float* __restrict__ x, const float* __restrict__ u,
    const float* __restrict__ W1, const float* __restrict__ b1,
    const float* __restrict__ W2, const float* __restrict__ b2,
    const float* __restrict__ gamma, const float* __restrict__ beta,
    const float* __restrict__ agg, const float* __restrict__ cnt,
    float* __restrict__ x_out, float* __restrict__ xsum)
{
    __shared__ __attribute__((aligned(16))) unsigned short hs[4][32][2][40];
    __shared__ float red[4][32][36];
    __shared__ float xsr[4][32];

    const int tid = threadIdx.x;
    const int w = tid >> 6, l = tid & 63, g = l >> 4, c = l & 15;
    const int csw = c >> 2;

    bf16x8 w1h[2][2], w1l[2][2];
#pragma unroll
    for (int kk = 0; kk < 2; ++kk)
#pragma unroll
        for (int nt = 0; nt < 2; ++nt) {
            bf16x8 h, lo;
#pragma unroll
            for (int j = 0; j < 8; ++j) {
                float f = W1[(size_t)(32 * kk + 8 * g + j) * 128 + 32 * w + 16 * nt + c];
                short sh, sl; splitf(f, sh, sl);
                h[j] = sh; lo[j] = sl;
            }
            w1h[kk][nt] = h; w1l[kk][nt] = lo;
        }

    bf16x8 w2h[2], w2l[2];
#pragma unroll
    for (int n2 = 0; n2 < 2; ++n2) {
        bf16x8 h, lo;
#pragma unroll
        for (int j = 0; j < 8; ++j) {
            float f = W2[(size_t)(32 * w + 8 * g + j) * 32 + 16 * n2 + c];
            short sh, sl; splitf(f, sh, sl);
            h[j] = sh; lo[j] = sl;
        }
        w2h[n2] = h; w2l[n2] = lo;
    }

    float b1v[2][4];
#pragma unroll
    for (int nt = 0; nt < 2; ++nt)
#pragma unroll
        for (int r = 0; r < 4; ++r)
            b1v[nt][r] = b1[32 * w + 16 * nt + 4 * g + r];

    const int ncol = tid & 31;
    const float b2c = b2[ncol], gc = gamma[ncol], btc = beta[ncol];

    const int nbase = blockIdx.x * 32;
    const int n0 = min(nbase + c, N_NODES_C - 1);
    const int n1 = min(nbase + 16 + c, N_NODES_C - 1);
    const float rcp0 = 1.f / fmaxf(cnt[n0], 1.f);
    const float rcp1 = 1.f / fmaxf(cnt[n1], 1.f);

    f32x4 acc[2][2];
#pragma unroll
    for (int t = 0; t < 2; ++t)
#pragma unroll
        for (int nt = 0; nt < 2; ++nt) {
            f32x4 z = {0.f, 0.f, 0.f, 0.f};
            acc[t][nt] = z;
        }

    {   // kk=0: x[n][8g..]
        bf16x8 bh0, bl0, bh1, bl1;
        ld8split(x + (size_t)n0 * 32 + 8 * g, 1.f, bh0, bl0);
        ld8split(x + (size_t)n1 * 32 + 8 * g, 1.f, bh1, bl1);
#pragma unroll
        for (int nt = 0; nt < 2; ++nt) {
            MFMA3(acc[0][nt], w1h[0][nt], w1l[0][nt], bh0, bl0);
            MFMA3(acc[1][nt], w1h[0][nt], w1l[0][nt], bh1, bl1);
        }
    }
    {   // kk=1: g<2 -> agg[n][8g]*rcp ; g>=2 -> u[8(g-2)]
        const float* p0 = (g < 2) ? (agg + (size_t)n0 * 16 + 8 * g) : (u + 8 * (g - 2));
        const float* p1 = (g < 2) ? (agg + (size_t)n1 * 16 + 8 * g) : (u + 8 * (g - 2));
        const float sc0 = (g < 2) ? rcp0 : 1.f;
        const float sc1 = (g < 2) ? rcp1 : 1.f;
        bf16x8 bh0, bl0, bh1, bl1;
        ld8split(p0, sc0, bh0, bl0); ld8split(p1, sc1, bh1, bl1);
#pragma unroll
        for (int nt = 0; nt < 2; ++nt) {
            MFMA3(acc[0][nt], w1h[1][nt], w1l[1][nt], bh0, bl0);
            MFMA3(acc[1][nt], w1h[1][nt], w1l[1][nt], bh1, bl1);
        }
    }

#pragma unroll
    for (int t = 0; t < 2; ++t)
#pragma unroll
        for (int nt = 0; nt < 2; ++nt) {
            short4 hi4, lo4;
            float v0 = fmaxf(acc[t][nt][0] + b1v[nt][0], 0.f);
            float v1 = fmaxf(acc[t][nt][1] + b1v[nt][1], 0.f);
            float v2 = fmaxf(acc[t][nt][2] + b1v[nt][2], 0.f);
            float v3 = fmaxf(acc[t][nt][3] + b1v[nt][3], 0.f);
            splitf(v0, hi4.x, lo4.x); splitf(v1, hi4.y, lo4.y);
            splitf(v2, hi4.z, lo4.z); splitf(v3, hi4.w, lo4.w);
            const int grp = ((2 * nt + (g >> 1)) ^ csw) * 8 + 4 * (g & 1);
            *reinterpret_cast<short4*>(&hs[w][16 * t + c][0][grp]) = hi4;
            *reinterpret_cast<short4*>(&hs[w][16 * t + c][1][grp]) = lo4;
        }

    f32x4 acc2[2][2];
#pragma unroll
    for (int t = 0; t < 2; ++t)
#pragma unroll
        for (int n2 = 0; n2 < 2; ++n2) {
            f32x4 z = {0.f, 0.f, 0.f, 0.f};
            acc2[t][n2] = z;
        }
#pragma unroll
    for (int t = 0; t < 2; ++t) {
        const int rg = (g ^ csw) * 8;
        bf16x8 a2h = *reinterpret_cast<const bf16x8*>(&hs[w][16 * t + c][0][rg]);
        bf16x8 a2l = *reinterpret_cast<const bf16x8*>(&hs[w][16 * t + c][1][rg]);
#pragma unroll
        for (int n2 = 0; n2 < 2; ++n2) {
            acc2[t][n2] = __builtin_amdgcn_mfma_f32_16x16x32_bf16(a2h, w2h[n2], acc2[t][n2], 0, 0, 0);
            acc2[t][n2] = __builtin_amdgcn_mfma_f32_16x16x32_bf16(a2l, w2h[n2], acc2[t][n2], 0, 0, 0);
            acc2[t][n2] = __builtin_amdgcn_mfma_f32_16x16x32_bf16(a2h, w2l[n2], acc2[t][n2], 0, 0, 0);
        }
    }

#pragma unroll
    for (int t = 0; t < 2; ++t)
#pragma unroll
        for (int n2 = 0; n2 < 2; ++n2)
#pragma unroll
            for (int r = 0; r < 4; ++r)
                red[w][16 * t + 4 * g + r][16 * n2 + c] = acc2[t][n2][r];
    __syncthreads();

    float xsl = 0.f;
#pragma unroll
    for (int pass = 0; pass < 4; ++pass) {
        const int nrow = (tid >> 5) + 8 * pass;  // 0..31
        float o = red[0][nrow][ncol] + red[1][nrow][ncol] +
                  red[2][nrow][ncol] + red[3][nrow][ncol] + b2c;
        o = fmaxf(o, 0.f);
        float s = o, q = o * o;
        s += __shfl_xor(s, 1);   q += __shfl_xor(q, 1);
        s += __shfl_xor(s, 2);   q += __shfl_xor(q, 2);
        s += __shfl_xor(s, 4);   q += __shfl_xor(q, 4);
        s += __shfl_xor(s, 8);   q += __shfl_xor(q, 8);
        s += __shfl_xor(s, 16);  q += __shfl_xor(q, 16);
        const float mu = s * (1.f / 32.f);
        const float var = fmaxf(q * (1.f / 32.f) - mu * mu, 0.f);
        const float val = (o - mu) * rsqrtf(var + EPS_C) * gc + btc;
        const int node = nbase + nrow;
        if (node < N_NODES_C) {
            x_out[(size_t)node * 32 + ncol] = val;
            xsl += val;
        }
    }

    xsl += __shfl_xor(xsl, 32);
    if (l < 32) xsr[w][l] = xsl;
    __syncthreads();
    if (tid < 32) atomicAdd(&xsum[tid], xsr[0][tid] + xsr[1][tid] + xsr[2][tid] + xsr[3][tid]);
}

// ===========================================================================
// Global MLP (tiny, f32): in[64] = [u, mean(x_out), mean(e_out)]
// ===========================================================================
__global__ __launch_bounds__(128) void global_kernel(
    const float* __restrict__ u,
    const float* __restrict__ W1, const float* __restrict__ b1,
    const float* __restrict__ W2, const float* __restrict__ b2,
    const float* __restrict__ esum, const float* __restrict__ xsum,
    float* __restrict__ u_out)
{
    __shared__ float gin[64];
    __shared__ float h[128];
    const int t = threadIdx.x;

    if (t < 16) gin[t] = u[t];
    else if (t < 48) gin[t] = xsum[t - 16] * (1.f / (float)N_NODES_C);
    else if (t < 64) gin[t] = esum[t - 48] * (1.f / (float)N_EDGES_C);
    __syncthreads();

    float hv = b1[t];
    for (int k = 0; k < 64; k++) hv = fmaf(gin[k], W1[(size_t)k * 128 + t], hv);
    h[t] = fmaxf(hv, 0.f);
    __syncthreads();

    if (t < 16) {
        float o = b2[t];
        for (int j = 0; j < 128; j++) o = fmaf(h[j], W2[(size_t)j * 16 + t], o);
        u_out[t] = fmaxf(o, 0.f);
    }
}

// ===========================================================================
extern "C" void kernel_launch(void* const* d_in, const int* in_sizes, int n_in,
                              void* d_out, int out_size, void* d_ws, size_t ws_size,
                              hipStream_t stream)
{
    const float* x    = (const float*)d_in[0];
    const float* ea   = (const float*)d_in[1];
    const float* u    = (const float*)d_in[2];
    const int*   src  = (const int*)d_in[3];
    const int*   dst  = (const int*)d_in[4];
    const float* eW1  = (const float*)d_in[5];
    const float* eb1  = (const float*)d_in[6];
    const float* eW2  = (const float*)d_in[7];
    const float* eb2  = (const float*)d_in[8];
    const float* eg   = (const float*)d_in[9];
    const float* ebt  = (const float*)d_in[10];
    const float* nW1  = (const float*)d_in[11];
    const float* nb1  = (const float*)d_in[12];
    const float* nW2  = (const float*)d_in[13];
    const float* nb2  = (const float*)d_in[14];
    const float* ng   = (const float*)d_in[15];
    const float* nbt  = (const float*)d_in[16];
    const float* gW1  = (const float*)d_in[17];
    const float* gb1  = (const float*)d_in[18];
    const float* gW2  = (const float*)d_in[19];
    const float* gb2  = (const float*)d_in[20];

    float* x_out = (float*)d_out;                              // 50000*32
    float* e_out = (float*)d_out + (size_t)N_NODES_C * 32;     // 1.6M*16
    float* u_out = e_out + (size_t)N_EDGES_C * 16;             // 16

    float* agg   = (float*)d_ws;                 // 800000
    float* cnt   = agg + 800000;                 // 50000
    float* esum  = cnt + 50000;                  // 16
    float* xsum  = esum + 16;                    // 32

    hipMemsetAsync(d_ws, 0, (size_t)(800000 + 50000 + 48) * sizeof(float), stream);

    edge_kernel<<<2000, 256, 0, stream>>>(
        x, ea, u, src, dst, eW1, eb1, eW2, eb2, eg, ebt, e_out, agg, cnt, esum);

    node_kernel<<<(N_NODES_C + 31) / 32, 256, 0, stream>>>(
        x, u, nW1, nb1, nW2, nb2, ng, nbt, agg, cnt, x_out, xsum);

    global_kernel<<<1, 128, 0, stream>>>(
        u, gW1, gb1, gW2, gb2, esum, xsum, u_out);
}